// Round 1
// baseline (144.711 us; speedup 1.0000x reference)
//
#include <hip/hip_runtime.h>
#include <math.h>

// ---------------- problem constants ----------------
#define N_TOTAL 2097152
#define WINDOW  20
#define M_ROLL  (N_TOTAL - WINDOW)      // 2097132 rolling windows
#define K_CVAR  62914u                  // int(N * 0.03)

// ---------------- kernel config --------------------
#define BS      256
#define TILE    2048
#define EPT     (TILE / BS)             // 8
#define NB_MAIN (N_TOTAL / TILE)        // 1024

// ---------------- ws layout (bytes) ----------------
// acc doubles: 0..6 = S1..S7 (sum r, sum r^2, sum|r|, #r>0, sum|dr|, sum signprod, sum|ds|)
//              7 = sum vol, 8 = sum vol^2, 9 = max_drawdown, 10 = v_edge, 11 = bottom-sum
#define ACC_OFF 0
#define SEL_OFF 96          // int[4]: b1, c_before1, u_edge, c_below
#define H1_OFF  112         // uint[2048]
#define H2_OFF  8304        // uint[2048]
#define DDT_OFF 16496       // float4[NB_MAIN] drawdown tuples (fully overwritten)
#define ZERO_BYTES 16496

__device__ __forceinline__ unsigned ordkey(float f) {
    unsigned b = __float_as_uint(f);
    return (b & 0x80000000u) ? ~b : (b | 0x80000000u);
}

__device__ __forceinline__ float sgnf(float x) {
    return (x > 0.f) ? 1.f : ((x < 0.f) ? -1.f : 0.f);
}

// ============ main fused pass: tile -> LDS, all elementwise reductions,
// rolling-window vol sums, per-block drawdown tuple, CVaR histogram pass 1 ====
__global__ __launch_bounds__(BS) void k_main(const float* __restrict__ pred,
                                             const float* __restrict__ ret,
                                             double* __restrict__ acc,
                                             unsigned* __restrict__ h1,
                                             float4* __restrict__ ddt)
{
    __shared__ float sh_r[TILE + WINDOW];   // r for [tileStart-1, tileStart+TILE+18]
    __shared__ float sh_s[TILE + 1];        // signals for [tileStart-1, tileStart+TILE-1]
    __shared__ unsigned lh[2048];
    __shared__ float sred[4][9];
    __shared__ float4 stup[4];

    const int tid = threadIdx.x;
    const int tileStart = blockIdx.x * TILE;

    for (int b = tid; b < 2048; b += BS) lh[b] = 0u;

    for (int idx = tid; idx < TILE + WINDOW; idx += BS) {
        int g = tileStart - 1 + idx;
        bool valid = (g >= 0) && (g < N_TOTAL);
        float p  = valid ? pred[g] : 0.f;
        float rt = valid ? ret[g]  : 0.f;
        float s = tanhf(p);
        sh_r[idx] = rt * s;
        if (idx <= TILE) sh_s[idx] = s;
    }
    __syncthreads();

    float s1=0.f,s2=0.f,s3=0.f,s4=0.f,s5=0.f,s6=0.f,s7=0.f,v1=0.f,v2=0.f;

    // interleaved element loop: lanes access consecutive LDS addresses
    for (int e = 0; e < EPT; ++e) {
        int j = tid + e * BS;           // 0..TILE-1
        int i = tileStart + j;          // global index
        float r = sh_r[j + 1];
        s1 += r;
        s2 += r * r;
        s3 += fabsf(r);
        s4 += (r > 0.f) ? 1.f : 0.f;
        if (i >= 1) {
            float rp = sh_r[j];
            s5 += fabsf(r - rp);
            s6 += sgnf(r) * sgnf(rp);
            s7 += fabsf(sh_s[j + 1] - sh_s[j]);
        }
        { unsigned u = ordkey(r); atomicAdd(&lh[u >> 21], 1u); }
        if (i < M_ROLL) {
            float ws = 0.f, wq = 0.f;
            #pragma unroll
            for (int w = 0; w < WINDOW; ++w) {
                float x = sh_r[j + 1 + w];
                ws += x; wq += x * x;
            }
            float var = (wq - ws * ws * (1.0f / WINDOW)) * (1.0f / (WINDOW - 1));
            var = fmaxf(var, 0.f);
            float vol = sqrtf(var);
            v1 += vol; v2 += vol * vol;
        }
    }

    // drawdown: per-thread contiguous chunk scan (order preserved)
    float tS, tMP, tMN, tDD;
    {
        int j0 = tid * EPT;
        float c = sh_r[j0 + 1];
        tMP = c; tMN = c; tDD = 0.f;
        for (int e = 1; e < EPT; ++e) {
            c += sh_r[j0 + 1 + e];
            tMP = fmaxf(tMP, c);
            tMN = fminf(tMN, c);
            tDD = fmaxf(tDD, tMP - c);
        }
        tS = c;
    }

    // wave-level ordered fold (ascending offsets keep segment order)
    for (int off = 1; off < 64; off <<= 1) {
        float oS  = __shfl_down(tS,  off);
        float oMP = __shfl_down(tMP, off);
        float oMN = __shfl_down(tMN, off);
        float oDD = __shfl_down(tDD, off);
        float nDD = fmaxf(fmaxf(tDD, oDD), tMP - (tS + oMN));
        float nMP = fmaxf(tMP, tS + oMP);
        float nMN = fminf(tMN, tS + oMN);
        tS += oS; tMP = nMP; tMN = nMN; tDD = nDD;
    }
    // wave-level sum reduce for the 9 scalar accumulators
    for (int off = 1; off < 64; off <<= 1) {
        s1 += __shfl_down(s1, off); s2 += __shfl_down(s2, off);
        s3 += __shfl_down(s3, off); s4 += __shfl_down(s4, off);
        s5 += __shfl_down(s5, off); s6 += __shfl_down(s6, off);
        s7 += __shfl_down(s7, off); v1 += __shfl_down(v1, off);
        v2 += __shfl_down(v2, off);
    }
    int wv = tid >> 6;
    if ((tid & 63) == 0) {
        sred[wv][0]=s1; sred[wv][1]=s2; sred[wv][2]=s3; sred[wv][3]=s4;
        sred[wv][4]=s5; sred[wv][5]=s6; sred[wv][6]=s7; sred[wv][7]=v1; sred[wv][8]=v2;
        stup[wv] = make_float4(tS, tMP, tMN, tDD);
    }
    __syncthreads();

    if (tid < 9) {
        float tot = sred[0][tid] + sred[1][tid] + sred[2][tid] + sred[3][tid];
        atomicAdd(&acc[tid], (double)tot);
    }
    if (tid == 0) {
        float4 a = stup[0];
        for (int w = 1; w < 4; ++w) {
            float4 b = stup[w];
            float nDD = fmaxf(fmaxf(a.w, b.w), a.y - (a.x + b.z));
            float nMP = fmaxf(a.y, a.x + b.y);
            float nMN = fminf(a.z, a.x + b.z);
            a.x += b.x; a.y = nMP; a.z = nMN; a.w = nDD;
        }
        ddt[blockIdx.x] = a;
    }
    for (int b = tid; b < 2048; b += BS) {
        unsigned c = lh[b];
        if (c) atomicAdd(&h1[b], c);
    }
}

// ============ combine 1: drawdown ordered tree + hist1 scan -> bucket b1 =====
__global__ __launch_bounds__(256) void k_combine1(double* __restrict__ acc,
                                                  const float4* __restrict__ ddt,
                                                  const unsigned* __restrict__ h1,
                                                  int* __restrict__ sel)
{
    __shared__ double sS[256], sMP[256], sMN[256], sDD[256];
    __shared__ unsigned lh[2048];
    __shared__ unsigned csum[256];

    int t = threadIdx.x;

    // fold 4 consecutive block tuples per thread (in order), in double
    double S, MP, MN, DD;
    {
        float4 a = ddt[t * 4];
        S = a.x; MP = a.y; MN = a.z; DD = a.w;
        for (int q = 1; q < 4; ++q) {
            float4 b = ddt[t * 4 + q];
            double nDD = fmax(fmax(DD, (double)b.w), MP - (S + (double)b.z));
            double nMP = fmax(MP, S + (double)b.y);
            double nMN = fmin(MN, S + (double)b.z);
            S += (double)b.x; MP = nMP; MN = nMN; DD = nDD;
        }
    }
    sS[t] = S; sMP[t] = MP; sMN[t] = MN; sDD[t] = DD;
    __syncthreads();
    for (int off = 1; off < 256; off <<= 1) {
        if ((t & (2 * off - 1)) == 0) {
            double aS=sS[t], aMP=sMP[t], aMN=sMN[t], aDD=sDD[t];
            double bS=sS[t+off], bMP=sMP[t+off], bMN=sMN[t+off], bDD=sDD[t+off];
            sDD[t] = fmax(fmax(aDD, bDD), aMP - (aS + bMN));
            sMP[t] = fmax(aMP, aS + bMP);
            sMN[t] = fmin(aMN, aS + bMN);
            sS[t]  = aS + bS;
        }
        __syncthreads();
    }
    if (t == 0) acc[9] = fmax(sDD[0], 0.0);

    // hist1 scan: find bucket b1 containing the K-th smallest
    for (int b = t; b < 2048; b += 256) lh[b] = h1[b];
    __syncthreads();
    unsigned cs = 0;
    for (int q = 0; q < 8; ++q) cs += lh[t * 8 + q];
    csum[t] = cs;
    __syncthreads();
    for (int off = 1; off < 256; off <<= 1) {
        unsigned y = (t >= off) ? csum[t - off] : 0u;
        __syncthreads();
        csum[t] += y;
        __syncthreads();
    }
    unsigned incl = csum[t], excl = incl - cs;
    if (excl < K_CVAR && incl >= K_CVAR) {
        unsigned cum = excl;
        int b1 = t * 8;
        for (int q = 0; q < 8; ++q) {
            unsigned h = lh[t * 8 + q];
            if (cum + h >= K_CVAR) { b1 = t * 8 + q; break; }
            cum += h;
        }
        sel[0] = b1;
        sel[1] = (int)cum;
    }
}

// ============ CVaR pass 2 histogram over mid 11 bits =========================
__global__ __launch_bounds__(BS) void k_hist2(const float* __restrict__ pred,
                                              const float* __restrict__ ret,
                                              const int* __restrict__ sel,
                                              unsigned* __restrict__ h2)
{
    unsigned b1 = (unsigned)sel[0];
    int stride = gridDim.x * blockDim.x;
    for (int i = blockIdx.x * blockDim.x + threadIdx.x; i < N_TOTAL; i += stride) {
        float r = ret[i] * tanhf(pred[i]);
        unsigned u = ordkey(r);
        if ((u >> 21) == b1) atomicAdd(&h2[(u >> 10) & 0x7FFu], 1u);
    }
}

// ============ combine 2: hist2 scan -> exact-ish edge key ====================
__global__ __launch_bounds__(256) void k_combine2(double* __restrict__ acc,
                                                  const unsigned* __restrict__ h2,
                                                  int* __restrict__ sel)
{
    __shared__ unsigned lh[2048];
    __shared__ unsigned csum[256];
    int t = threadIdx.x;
    unsigned base = (unsigned)sel[1];

    for (int b = t; b < 2048; b += 256) lh[b] = h2[b];
    __syncthreads();
    unsigned cs = 0;
    for (int q = 0; q < 8; ++q) cs += lh[t * 8 + q];
    csum[t] = cs;
    __syncthreads();
    for (int off = 1; off < 256; off <<= 1) {
        unsigned y = (t >= off) ? csum[t - off] : 0u;
        __syncthreads();
        csum[t] += y;
        __syncthreads();
    }
    unsigned incl = base + csum[t], excl = incl - cs;
    if (excl < K_CVAR && incl >= K_CVAR) {
        unsigned cum = excl;
        int b2 = t * 8;
        for (int q = 0; q < 8; ++q) {
            unsigned h = lh[t * 8 + q];
            if (cum + h >= K_CVAR) { b2 = t * 8 + q; break; }
            cum += h;
        }
        unsigned ue = (((unsigned)sel[0]) << 21) | (((unsigned)b2) << 10);
        unsigned bits = (ue & 0x80000000u) ? (ue ^ 0x80000000u) : ~ue;
        sel[2] = (int)ue;
        sel[3] = (int)cum;
        acc[10] = (double)__uint_as_float(bits);
    }
}

// ============ sum of all r strictly below the edge key =======================
__global__ __launch_bounds__(BS) void k_bsum(const float* __restrict__ pred,
                                             const float* __restrict__ ret,
                                             const int* __restrict__ sel,
                                             double* __restrict__ acc)
{
    unsigned ue = (unsigned)sel[2];
    float lsum = 0.f;
    int stride = gridDim.x * blockDim.x;
    for (int i = blockIdx.x * blockDim.x + threadIdx.x; i < N_TOTAL; i += stride) {
        float r = ret[i] * tanhf(pred[i]);
        if (ordkey(r) < ue) lsum += r;
    }
    for (int off = 1; off < 64; off <<= 1) lsum += __shfl_down(lsum, off);
    __shared__ float sw[4];
    int tid = threadIdx.x;
    if ((tid & 63) == 0) sw[tid >> 6] = lsum;
    __syncthreads();
    if (tid == 0) {
        float tot = sw[0] + sw[1] + sw[2] + sw[3];
        if (tot != 0.f) atomicAdd(&acc[11], (double)tot);
    }
}

// ============ final scalar assembly ==========================================
__global__ void k_final(const double* __restrict__ acc,
                        const int* __restrict__ sel,
                        float* __restrict__ out)
{
    if (threadIdx.x != 0 || blockIdx.x != 0) return;
    double n = (double)N_TOTAL;
    double S1 = acc[0], S2 = acc[1], S3 = acc[2], S4 = acc[3];
    double S5 = acc[4], S6 = acc[5], S7 = acc[6], V1 = acc[7], V2 = acc[8];
    double dd = acc[9], vedge = acc[10], bsum = acc[11];

    double mean_r = S1 / n;
    double var_r = (S2 - S1 * S1 / n) / (n - 1.0);
    if (var_r < 0.0) var_r = 0.0;
    double std_r = sqrt(var_r) + 1e-8;
    double base_sharpe = mean_r / std_r;

    double m = (double)M_ROLL;
    double var_v = (V2 - V1 * V1 / m) / (m - 1.0);
    if (var_v < 0.0) var_v = 0.0;
    double vs = 1.0 / (sqrt(var_v) + 1e-6);
    double es = base_sharpe * (1.0 + 0.1 * vs);

    double rm = S3 / n;
    double pf = S4 / n;
    double rs = 1.0 / (S5 / (n - 1.0) + 1e-6);
    double mc = S6 / (n - 1.0);
    double ddp = dd - 0.05; if (ddp < 0.0) ddp = 0.0;
    double sc = S7 / (n - 1.0);
    double ss = 1.0 / (sc + 1e-6);

    int c_below = sel[3];
    double cvar = -(bsum + ((double)((int)K_CVAR - c_below)) * vedge) / (double)K_CVAR;

    double SC = 0.4 * es + 0.25 * rm + 0.15 * pf + 0.1 * mc + 0.05 * rs + 0.05 * ss;
    double RP = 0.05 * cvar + 0.02 * ddp + 0.01 * sc;
    out[0] = (float)(-(0.6 * rm + 0.4 * SC - RP));
}

// ============ launch =========================================================
extern "C" void kernel_launch(void* const* d_in, const int* in_sizes, int n_in,
                              void* d_out, int out_size, void* d_ws, size_t ws_size,
                              hipStream_t stream)
{
    const float* pred = (const float*)d_in[0];
    const float* ret  = (const float*)d_in[1];
    char* ws = (char*)d_ws;
    double*   acc = (double*)(ws + ACC_OFF);
    int*      sel = (int*)(ws + SEL_OFF);
    unsigned* h1  = (unsigned*)(ws + H1_OFF);
    unsigned* h2  = (unsigned*)(ws + H2_OFF);
    float4*   ddt = (float4*)(ws + DDT_OFF);

    hipMemsetAsync(ws, 0, ZERO_BYTES, stream);
    k_main<<<NB_MAIN, BS, 0, stream>>>(pred, ret, acc, h1, ddt);
    k_combine1<<<1, 256, 0, stream>>>(acc, ddt, h1, sel);
    k_hist2<<<2048, BS, 0, stream>>>(pred, ret, sel, h2);
    k_combine2<<<1, 256, 0, stream>>>(acc, h2, sel);
    k_bsum<<<2048, BS, 0, stream>>>(pred, ret, sel, acc);
    k_final<<<1, 64, 0, stream>>>(acc, sel, (float*)d_out);
}

// Round 2
// 109.756 us; speedup vs baseline: 1.3185x; 1.3185x over previous
//
#include <hip/hip_runtime.h>
#include <math.h>

// ---------------- problem constants ----------------
#define N_TOTAL 2097152
#define WINDOW  20
#define M_ROLL  (N_TOTAL - WINDOW)      // 2097132 rolling windows
#define K_CVAR  62914u                  // int(N * 0.03)

// ---------------- kernel config --------------------
#define BS      256
#define TILE    2048
#define EPT     (TILE / BS)             // 8
#define NB_MAIN (N_TOTAL / TILE)        // 1024
#define NBINS   2048                    // sign + 8 exp + 2 mantissa bits (u >> 21)
#define CB      1024                    // combine block size

// ---------------- ws layout (bytes) ----------------
// acc doubles: 0..6 = S1..S7 (sum r, sum r^2, sum|r|, #r>0, sum|dr|, sum signprod, sum|ds|)
//              7 = sum vol, 8 = sum vol^2
#define ACC_OFF  0
#define HCNT_OFF 128                    // uint[2048]
#define HSUM_OFF 8320                   // float[2048]
#define DDT_OFF  16512                  // float4[1024] (fully overwritten, no init)
#define ZERO_BYTES 16512

__device__ __forceinline__ unsigned ordkey(float f) {
    unsigned b = __float_as_uint(f);
    return (b & 0x80000000u) ? ~b : (b | 0x80000000u);
}
__device__ __forceinline__ float inv_ordkey(unsigned u) {
    return __uint_as_float((u & 0x80000000u) ? (u ^ 0x80000000u) : ~u);
}
__device__ __forceinline__ float sgnf(float x) {
    return (x > 0.f) ? 1.f : ((x < 0.f) ? -1.f : 0.f);
}

// ============ main fused pass: one 16MB sweep does everything ================
__global__ __launch_bounds__(BS) void k_main(const float* __restrict__ pred,
                                             const float* __restrict__ ret,
                                             double* __restrict__ acc,
                                             unsigned* __restrict__ hcnt,
                                             float* __restrict__ hsum,
                                             float4* __restrict__ ddt)
{
    __shared__ float sh_r[TILE + WINDOW];   // r for [tileStart-1, tileStart+TILE+18]
    __shared__ float sh_s[TILE + 1];        // signals for [tileStart-1, tileStart+TILE-1]
    __shared__ unsigned lc[NBINS];
    __shared__ float    ls[NBINS];
    __shared__ float sred[4][9];
    __shared__ float4 stup[4];

    const int tid = threadIdx.x;
    const int tileStart = blockIdx.x * TILE;

    for (int b = tid; b < NBINS; b += BS) { lc[b] = 0u; ls[b] = 0.f; }

    for (int idx = tid; idx < TILE + WINDOW; idx += BS) {
        int g = tileStart - 1 + idx;
        bool valid = (g >= 0) && (g < N_TOTAL);
        float p  = valid ? pred[g] : 0.f;
        float rt = valid ? ret[g]  : 0.f;
        float s = tanhf(p);
        sh_r[idx] = rt * s;
        if (idx <= TILE) sh_s[idx] = s;
    }
    __syncthreads();

    float s1=0.f,s2=0.f,s3=0.f,s4=0.f,s5=0.f,s6=0.f,s7=0.f,v1=0.f,v2=0.f;

    // interleaved element loop: lanes access consecutive LDS addresses
    for (int e = 0; e < EPT; ++e) {
        int j = tid + e * BS;           // 0..TILE-1
        int i = tileStart + j;          // global index
        float r = sh_r[j + 1];
        s1 += r;
        s2 += r * r;
        s3 += fabsf(r);
        s4 += (r > 0.f) ? 1.f : 0.f;
        if (i >= 1) {
            float rp = sh_r[j];
            s5 += fabsf(r - rp);
            s6 += sgnf(r) * sgnf(rp);
            s7 += fabsf(sh_s[j + 1] - sh_s[j]);
        }
        {
            unsigned u = ordkey(r);
            unsigned bin = u >> 21;
            atomicAdd(&lc[bin], 1u);
            atomicAdd(&ls[bin], r);
        }
        if (i < M_ROLL) {
            float ws = 0.f, wq = 0.f;
            #pragma unroll
            for (int w = 0; w < WINDOW; ++w) {
                float x = sh_r[j + 1 + w];
                ws += x; wq += x * x;
            }
            float var = (wq - ws * ws * (1.0f / WINDOW)) * (1.0f / (WINDOW - 1));
            var = fmaxf(var, 0.f);
            float vol = sqrtf(var);
            v1 += vol; v2 += vol * vol;
        }
    }

    // drawdown: per-thread contiguous chunk scan (order preserved)
    float tS, tMP, tMN, tDD;
    {
        int j0 = tid * EPT;
        float c = sh_r[j0 + 1];
        tMP = c; tMN = c; tDD = 0.f;
        for (int e = 1; e < EPT; ++e) {
            c += sh_r[j0 + 1 + e];
            tMP = fmaxf(tMP, c);
            tMN = fminf(tMN, c);
            tDD = fmaxf(tDD, tMP - c);
        }
        tS = c;
    }

    // wave-level ordered fold (ascending offsets keep segment order)
    for (int off = 1; off < 64; off <<= 1) {
        float oS  = __shfl_down(tS,  off);
        float oMP = __shfl_down(tMP, off);
        float oMN = __shfl_down(tMN, off);
        float oDD = __shfl_down(tDD, off);
        float nDD = fmaxf(fmaxf(tDD, oDD), tMP - (tS + oMN));
        float nMP = fmaxf(tMP, tS + oMP);
        float nMN = fminf(tMN, tS + oMN);
        tS += oS; tMP = nMP; tMN = nMN; tDD = nDD;
    }
    // wave-level sum reduce for the 9 scalar accumulators
    for (int off = 1; off < 64; off <<= 1) {
        s1 += __shfl_down(s1, off); s2 += __shfl_down(s2, off);
        s3 += __shfl_down(s3, off); s4 += __shfl_down(s4, off);
        s5 += __shfl_down(s5, off); s6 += __shfl_down(s6, off);
        s7 += __shfl_down(s7, off); v1 += __shfl_down(v1, off);
        v2 += __shfl_down(v2, off);
    }
    int wv = tid >> 6;
    if ((tid & 63) == 0) {
        sred[wv][0]=s1; sred[wv][1]=s2; sred[wv][2]=s3; sred[wv][3]=s4;
        sred[wv][4]=s5; sred[wv][5]=s6; sred[wv][6]=s7; sred[wv][7]=v1; sred[wv][8]=v2;
        stup[wv] = make_float4(tS, tMP, tMN, tDD);
    }
    __syncthreads();

    if (tid < 9) {
        float tot = sred[0][tid] + sred[1][tid] + sred[2][tid] + sred[3][tid];
        atomicAdd(&acc[tid], (double)tot);
    }
    if (tid == 0) {
        float4 a = stup[0];
        for (int w = 1; w < 4; ++w) {
            float4 b = stup[w];
            float nDD = fmaxf(fmaxf(a.w, b.w), a.y - (a.x + b.z));
            float nMP = fmaxf(a.y, a.x + b.y);
            float nMN = fminf(a.z, a.x + b.z);
            a.x += b.x; a.y = nMP; a.z = nMN; a.w = nDD;
        }
        ddt[blockIdx.x] = a;
    }
    for (int b = tid; b < NBINS; b += BS) {
        unsigned c = lc[b];
        if (c) {
            atomicAdd(&hcnt[b], c);
            atomicAdd(&hsum[b], ls[b]);
        }
    }
}

// ============ combine: drawdown tree + hist scan + CVaR + final formula ======
__global__ __launch_bounds__(CB) void k_combine(const double* __restrict__ acc,
                                                const unsigned* __restrict__ hcnt,
                                                const float* __restrict__ hsum,
                                                const float4* __restrict__ ddt,
                                                float* __restrict__ out)
{
    __shared__ double dS[CB], dMP[CB], dMN[CB], dDD[CB];
    __shared__ unsigned scn[CB];
    __shared__ int s_edge;
    __shared__ unsigned s_cbelow;

    const int t = threadIdx.x;

    // ---- A: drawdown ordered tree (double) ----
    float4 a = ddt[t];
    dS[t] = a.x; dMP[t] = a.y; dMN[t] = a.z; dDD[t] = a.w;
    __syncthreads();
    for (int off = 1; off < CB; off <<= 1) {
        if ((t & (2 * off - 1)) == 0) {
            double aS=dS[t], aMP=dMP[t], aMN=dMN[t], aDD=dDD[t];
            double bS=dS[t+off], bMP=dMP[t+off], bMN=dMN[t+off], bDD=dDD[t+off];
            dDD[t] = fmax(fmax(aDD, bDD), aMP - (aS + bMN));
            dMP[t] = fmax(aMP, aS + bMP);
            dMN[t] = fmin(aMN, aS + bMN);
            dS[t]  = aS + bS;
        }
        __syncthreads();
    }
    // dDD[0] now holds global max drawdown (left untouched below)

    // ---- B: histogram scan (2 bins per thread) ----
    unsigned c0 = hcnt[2 * t], c1 = hcnt[2 * t + 1];
    unsigned cs = c0 + c1;
    scn[t] = cs;
    __syncthreads();
    for (int off = 1; off < CB; off <<= 1) {
        unsigned y = (t >= off) ? scn[t - off] : 0u;
        __syncthreads();
        scn[t] += y;
        __syncthreads();
    }
    unsigned incl = scn[t], excl = incl - cs;
    if (excl < K_CVAR && incl >= K_CVAR) {
        if (excl + c0 >= K_CVAR) { s_edge = 2 * t;     s_cbelow = excl; }
        else                     { s_edge = 2 * t + 1; s_cbelow = excl + c0; }
    }
    __syncthreads();
    const int be = s_edge;
    const unsigned cb = s_cbelow;

    // ---- C: sum of r over bins strictly below the edge bin (double) ----
    double part = 0.0;
    if (2 * t     < be) part += (double)hsum[2 * t];
    if (2 * t + 1 < be) part += (double)hsum[2 * t + 1];
    dS[t] = part;                       // dS reuse is safe (only dDD[0] needed later)
    __syncthreads();
    for (int off = CB / 2; off >= 1; off >>= 1) {
        if (t < off) dS[t] += dS[t + off];
        __syncthreads();
    }

    if (t == 0) {
        double n = (double)N_TOTAL;
        double S1 = acc[0], S2 = acc[1], S3 = acc[2], S4 = acc[3];
        double S5 = acc[4], S6 = acc[5], S7 = acc[6], V1 = acc[7], V2 = acc[8];

        double mean_r = S1 / n;
        double var_r = (S2 - S1 * S1 / n) / (n - 1.0);
        if (var_r < 0.0) var_r = 0.0;
        double std_r = sqrt(var_r) + 1e-8;
        double base_sharpe = mean_r / std_r;

        double m = (double)M_ROLL;
        double var_v = (V2 - V1 * V1 / m) / (m - 1.0);
        if (var_v < 0.0) var_v = 0.0;
        double vs = 1.0 / (sqrt(var_v) + 1e-6);
        double es = base_sharpe * (1.0 + 0.1 * vs);

        double rm = S3 / n;
        double pf = S4 / n;
        double rs = 1.0 / (S5 / (n - 1.0) + 1e-6);
        double mc = S6 / (n - 1.0);
        double dd = fmax(dDD[0], 0.0);
        double ddp = dd - 0.05; if (ddp < 0.0) ddp = 0.0;
        double sc = S7 / (n - 1.0);
        double ss = 1.0 / (sc + 1e-6);

        // CVaR: full bins below edge + interpolated draw from the edge bin
        double bsum = dS[0];
        unsigned ce = hcnt[be];
        double mneed = (double)(K_CVAR - cb);
        double elo = (double)inv_ordkey(((unsigned)be) << 21);
        double ehi = (double)inv_ordkey(((unsigned)(be + 1)) << 21);
        double edgev = elo + (mneed / (2.0 * (double)(ce > 0u ? ce : 1u))) * (ehi - elo);
        double cvar = -(bsum + mneed * edgev) / (double)K_CVAR;

        double SC = 0.4 * es + 0.25 * rm + 0.15 * pf + 0.1 * mc + 0.05 * rs + 0.05 * ss;
        double RP = 0.05 * cvar + 0.02 * ddp + 0.01 * sc;
        out[0] = (float)(-(0.6 * rm + 0.4 * SC - RP));
    }
}

// ============ launch =========================================================
extern "C" void kernel_launch(void* const* d_in, const int* in_sizes, int n_in,
                              void* d_out, int out_size, void* d_ws, size_t ws_size,
                              hipStream_t stream)
{
    const float* pred = (const float*)d_in[0];
    const float* ret  = (const float*)d_in[1];
    char* ws = (char*)d_ws;
    double*   acc  = (double*)(ws + ACC_OFF);
    unsigned* hcnt = (unsigned*)(ws + HCNT_OFF);
    float*    hsum = (float*)(ws + HSUM_OFF);
    float4*   ddt  = (float4*)(ws + DDT_OFF);

    hipMemsetAsync(ws, 0, ZERO_BYTES, stream);
    k_main<<<NB_MAIN, BS, 0, stream>>>(pred, ret, acc, hcnt, hsum, ddt);
    k_combine<<<1, CB, 0, stream>>>(acc, hcnt, hsum, ddt, (float*)d_out);
}